// Round 19
// baseline (40.214 us; speedup 1.0000x reference)
//
#include <hip/hip_runtime.h>

#define N 4096
#define F 64
#define H 8
#define W1S (2 * F + 1)   // 129
#define PCH 128           // partial chunks (32 rows each)

typedef float f4 __attribute__((ext_vector_type(4)));

// ---------------------------------------------------------------------------
// K1 "prep": 2080 blocks x 256. No atomics, no memset.
//  blocks 0-2047: column sums of A -> partial[128][4096].
//    block b: stripe st=b&15 (256 cols), chunk ch=b>>4 (32 rows).
//    thread t -> col j=st*256+t, scalar loads (block reads 1KB/row),
//    32 independent loads pipelined 4-wide. 8 blocks/CU (full occupancy).
//  blocks 2048-2063: aj[n][8]  = b1 + E.W1a      (running accum, low VGPR)
//  blocks 2064-2079: bkF_T[k][n] = sum_f E.W1b   (coalesced per-k stores)
//                    + diag[n] = A[n][n]
// ---------------------------------------------------------------------------
__global__ __launch_bounds__(256) void prep(const float* __restrict__ A,
                                            const float* __restrict__ emb,
                                            const float* __restrict__ W1,
                                            const float* __restrict__ b1,
                                            float* __restrict__ partial,
                                            float* __restrict__ aj,
                                            float* __restrict__ bkF,
                                            float* __restrict__ diag) {
    const int b = blockIdx.x;
    const int t = threadIdx.x;

    if (b < 2048) {
        int st = b & 15;
        int ch = b >> 4;
        int j  = st * 256 + t;
        const float* p = A + (size_t)(ch * 32) * N + j;
        float s0 = 0.f, s1 = 0.f, s2 = 0.f, s3 = 0.f;
#pragma unroll 8
        for (int r = 0; r < 32; r += 4) {
            s0 += p[(size_t)(r + 0) * N];
            s1 += p[(size_t)(r + 1) * N];
            s2 += p[(size_t)(r + 2) * N];
            s3 += p[(size_t)(r + 3) * N];
        }
        partial[(size_t)ch * N + j] = (s0 + s1) + (s2 + s3);
    } else {
        int idx = b - 2048;                // 0..31
        int n = (idx & 15) * 256 + t;
        if (idx < 16) {
            float av[H];
#pragma unroll
            for (int k = 0; k < H; ++k) av[k] = b1[k];
#pragma unroll
            for (int f = 0; f < F; ++f) {
                float e = emb[(size_t)f * N + n];
#pragma unroll
                for (int k = 0; k < H; ++k) av[k] += e * W1[k * W1S + f];
            }
#pragma unroll
            for (int k = 0; k < H; ++k) aj[n * H + k] = av[k];
        } else {
            float bv[H];
#pragma unroll
            for (int k = 0; k < H; ++k) bv[k] = 0.f;
#pragma unroll
            for (int f = 0; f < F; ++f) {
                float e = emb[(size_t)f * N + n];
#pragma unroll
                for (int k = 0; k < H; ++k) bv[k] += e * W1[k * W1S + F + f];
            }
#pragma unroll
            for (int k = 0; k < H; ++k) bkF[(size_t)k * N + n] = bv[k];
            diag[n] = A[(size_t)n * N + n];
        }
    }
}

// ---------------------------------------------------------------------------
// K2 "fuse": grid (16,64) = 1024 blocks, tile 256 cols x 64 rows.
// Byte-identical to R18 (best measured) except PCH loop = 128.
// Phase A: thread t -> col j=j0+t: s = sum_{ch<128} partial[ch][j];
//          sw = (s - diag[j])/4095;
//          bks[k][t] = bkF_T[k][j] + sw*W1[k][128]   (LDS [8][260])
// Phase B: tx=t&63 -> 4 cols (bk4 regs), ty=t>>6 -> 16 rows; aj loads
//          wave-uniform broadcast; float4 stores 1KB/wave contiguous.
// ---------------------------------------------------------------------------
__global__ __launch_bounds__(256, 8) void fuse(const float* __restrict__ W1,
                                               const float* __restrict__ aj,
                                               const float* __restrict__ bkF,
                                               const float* __restrict__ partial,
                                               const float* __restrict__ diag,
                                               const float* __restrict__ W2,
                                               const float* __restrict__ b2,
                                               float* __restrict__ out) {
    __shared__ float bks[H][260];          // 1040B row stride, 16B-aligned

    const int t  = threadIdx.x;
    const int j0 = blockIdx.x * 256;
    const int i0 = blockIdx.y * 64;

    {
        int j = j0 + t;
        float s = 0.f;
        const float* pp = partial + j;
#pragma unroll 16
        for (int ch = 0; ch < PCH; ++ch) s += pp[(size_t)ch * N];
        float sw = (s - diag[j]) * (1.0f / (float)(N - 1));
#pragma unroll
        for (int k = 0; k < H; ++k)
            bks[k][t] = bkF[(size_t)k * N + j] + sw * W1[k * W1S + 2 * F];
    }
    __syncthreads();

    const int tx = t & 63;
    const int ty = __builtin_amdgcn_readfirstlane(t >> 6);

    f4 bk4[H];
#pragma unroll
    for (int k = 0; k < H; ++k) bk4[k] = *(const f4*)&bks[k][tx * 4];

    float w2[H];
#pragma unroll
    for (int k = 0; k < H; ++k) w2[k] = W2[k];   // W2[0][k]
    const float b20 = b2[0];

    const int j = j0 + tx * 4;
#pragma unroll
    for (int r = 0; r < 16; ++r) {
        int i = i0 + ty * 16 + r;
        f4 alo = *(const f4*)(aj + (size_t)i * H);      // wave-uniform addr
        f4 ahi = *(const f4*)(aj + (size_t)i * H + 4);
        float a[H] = {alo.x, alo.y, alo.z, alo.w, ahi.x, ahi.y, ahi.z, ahi.w};

        f4 res = {b20, b20, b20, b20};
#pragma unroll
        for (int k = 0; k < H; ++k) {
            f4 tt = bk4[k];
            tt.x = fmaxf(a[k] + tt.x, 0.f);
            tt.y = fmaxf(a[k] + tt.y, 0.f);
            tt.z = fmaxf(a[k] + tt.z, 0.f);
            tt.w = fmaxf(a[k] + tt.w, 0.f);
            res.x += tt.x * w2[k];
            res.y += tt.y * w2[k];
            res.z += tt.z * w2[k];
            res.w += tt.w * w2[k];
        }
        *(f4*)(out + (size_t)i * N + j) = res;
    }
}

extern "C" void kernel_launch(void* const* d_in, const int* in_sizes, int n_in,
                              void* d_out, int out_size, void* d_ws, size_t ws_size,
                              hipStream_t stream) {
    const float* adj = (const float*)d_in[0];   // (1, N, N)
    const float* emb = (const float*)d_in[1];   // (1, F, N)
    const float* W1  = (const float*)d_in[2];   // (H, 2F+1)
    const float* b1  = (const float*)d_in[3];   // (H,)
    const float* W2  = (const float*)d_in[4];   // (8, H)
    const float* b2  = (const float*)d_in[5];   // (8,)
    float* out = (float*)d_out;

    float* partial = (float*)d_ws;              // 128*4096 floats = 2 MB
    float* aj   = partial + (size_t)PCH * N;    // N*H floats = 128 KB
    float* bkF  = aj + (size_t)N * H;           // H*N floats = 128 KB
    float* diag = bkF + (size_t)H * N;          // N floats = 16 KB

    prep<<<dim3(2080), 256, 0, stream>>>(adj, emb, W1, b1, partial, aj, bkF, diag);
    fuse<<<dim3(N / 256, N / 64), 256, 0, stream>>>(W1, aj, bkF, partial, diag,
                                                    W2, b2, out);
}

// Round 24
// 34.078 us; speedup vs baseline: 1.1801x; 1.1801x over previous
//
#include <hip/hip_runtime.h>

#define N 4096
#define F 64
#define H 8
#define W1S (2 * F + 1)   // 129
#define PCH 64            // partial chunks (64 rows each) — measured optimum

typedef float f4 __attribute__((ext_vector_type(4)));

// ---------------------------------------------------------------------------
// K1 "prep": 1056 blocks x 256. No atomics, no memset.
//  blocks 0-1023: column sums of A -> partial[64][4096].
//    block b: stripe st=b&15 (256 cols), chunk ch=b>>4 (64 rows).
//    thread t -> col j=st*256+t, scalar loads (block reads 1KB/row),
//    64 independent loads pipelined 4-wide. 4 blocks/CU.
//    (PCH sweep measured: 32ch/128rows=39.4us, 64ch/64rows=33.96us,
//     128ch/32rows=40.2us — 64 is the page-locality/occupancy optimum.)
//  blocks 1024-1039: aj[n][8]  = b1 + E.W1a      (running accum, low VGPR)
//  blocks 1040-1055: bkF_T[k][n] = sum_f E.W1b   (coalesced per-k stores)
//                    + diag[n] = A[n][n]
// ---------------------------------------------------------------------------
__global__ __launch_bounds__(256) void prep(const float* __restrict__ A,
                                            const float* __restrict__ emb,
                                            const float* __restrict__ W1,
                                            const float* __restrict__ b1,
                                            float* __restrict__ partial,
                                            float* __restrict__ aj,
                                            float* __restrict__ bkF,
                                            float* __restrict__ diag) {
    const int b = blockIdx.x;
    const int t = threadIdx.x;

    if (b < 1024) {
        int st = b & 15;
        int ch = b >> 4;
        int j  = st * 256 + t;
        const float* p = A + (size_t)(ch * 64) * N + j;
        float s0 = 0.f, s1 = 0.f, s2 = 0.f, s3 = 0.f;
#pragma unroll 8
        for (int r = 0; r < 64; r += 4) {
            s0 += p[(size_t)(r + 0) * N];
            s1 += p[(size_t)(r + 1) * N];
            s2 += p[(size_t)(r + 2) * N];
            s3 += p[(size_t)(r + 3) * N];
        }
        partial[(size_t)ch * N + j] = (s0 + s1) + (s2 + s3);
    } else {
        int idx = b - 1024;                // 0..31
        int n = (idx & 15) * 256 + t;
        if (idx < 16) {
            float av[H];
#pragma unroll
            for (int k = 0; k < H; ++k) av[k] = b1[k];
#pragma unroll
            for (int f = 0; f < F; ++f) {
                float e = emb[(size_t)f * N + n];
#pragma unroll
                for (int k = 0; k < H; ++k) av[k] += e * W1[k * W1S + f];
            }
#pragma unroll
            for (int k = 0; k < H; ++k) aj[n * H + k] = av[k];
        } else {
            float bv[H];
#pragma unroll
            for (int k = 0; k < H; ++k) bv[k] = 0.f;
#pragma unroll
            for (int f = 0; f < F; ++f) {
                float e = emb[(size_t)f * N + n];
#pragma unroll
                for (int k = 0; k < H; ++k) bv[k] += e * W1[k * W1S + F + f];
            }
#pragma unroll
            for (int k = 0; k < H; ++k) bkF[(size_t)k * N + n] = bv[k];
            diag[n] = A[(size_t)n * N + n];
        }
    }
}

// ---------------------------------------------------------------------------
// K2 "fuse": grid (16,64) = 1024 blocks, tile 256 cols x 64 rows.
// Phase A: thread t -> col j=j0+t: s = sum_{ch<64} partial[ch][j];
//          sw = (s - diag[j])/4095;
//          bks[k][t] = bkF_T[k][j] + sw*W1[k][128]   (LDS [8][260])
// Phase B: tx=t&63 -> 4 cols (bk4 regs), ty=t>>6 -> 16 rows; aj loads
//          wave-uniform broadcast; float4 stores 1KB/wave contiguous.
// ---------------------------------------------------------------------------
__global__ __launch_bounds__(256, 8) void fuse(const float* __restrict__ W1,
                                               const float* __restrict__ aj,
                                               const float* __restrict__ bkF,
                                               const float* __restrict__ partial,
                                               const float* __restrict__ diag,
                                               const float* __restrict__ W2,
                                               const float* __restrict__ b2,
                                               float* __restrict__ out) {
    __shared__ float bks[H][260];          // 1040B row stride, 16B-aligned

    const int t  = threadIdx.x;
    const int j0 = blockIdx.x * 256;
    const int i0 = blockIdx.y * 64;

    {
        int j = j0 + t;
        float s = 0.f;
        const float* pp = partial + j;
#pragma unroll 16
        for (int ch = 0; ch < PCH; ++ch) s += pp[(size_t)ch * N];
        float sw = (s - diag[j]) * (1.0f / (float)(N - 1));
#pragma unroll
        for (int k = 0; k < H; ++k)
            bks[k][t] = bkF[(size_t)k * N + j] + sw * W1[k * W1S + 2 * F];
    }
    __syncthreads();

    const int tx = t & 63;
    const int ty = __builtin_amdgcn_readfirstlane(t >> 6);

    f4 bk4[H];
#pragma unroll
    for (int k = 0; k < H; ++k) bk4[k] = *(const f4*)&bks[k][tx * 4];

    float w2[H];
#pragma unroll
    for (int k = 0; k < H; ++k) w2[k] = W2[k];   // W2[0][k]
    const float b20 = b2[0];

    const int j = j0 + tx * 4;
#pragma unroll
    for (int r = 0; r < 16; ++r) {
        int i = i0 + ty * 16 + r;
        f4 alo = *(const f4*)(aj + (size_t)i * H);      // wave-uniform addr
        f4 ahi = *(const f4*)(aj + (size_t)i * H + 4);
        float a[H] = {alo.x, alo.y, alo.z, alo.w, ahi.x, ahi.y, ahi.z, ahi.w};

        f4 res = {b20, b20, b20, b20};
#pragma unroll
        for (int k = 0; k < H; ++k) {
            f4 tt = bk4[k];
            tt.x = fmaxf(a[k] + tt.x, 0.f);
            tt.y = fmaxf(a[k] + tt.y, 0.f);
            tt.z = fmaxf(a[k] + tt.z, 0.f);
            tt.w = fmaxf(a[k] + tt.w, 0.f);
            res.x += tt.x * w2[k];
            res.y += tt.y * w2[k];
            res.z += tt.z * w2[k];
            res.w += tt.w * w2[k];
        }
        *(f4*)(out + (size_t)i * N + j) = res;
    }
}

extern "C" void kernel_launch(void* const* d_in, const int* in_sizes, int n_in,
                              void* d_out, int out_size, void* d_ws, size_t ws_size,
                              hipStream_t stream) {
    const float* adj = (const float*)d_in[0];   // (1, N, N)
    const float* emb = (const float*)d_in[1];   // (1, F, N)
    const float* W1  = (const float*)d_in[2];   // (H, 2F+1)
    const float* b1  = (const float*)d_in[3];   // (H,)
    const float* W2  = (const float*)d_in[4];   // (8, H)
    const float* b2  = (const float*)d_in[5];   // (8,)
    float* out = (float*)d_out;

    float* partial = (float*)d_ws;              // 64*4096 floats = 1 MB
    float* aj   = partial + (size_t)PCH * N;    // N*H floats = 128 KB
    float* bkF  = aj + (size_t)N * H;           // H*N floats = 128 KB
    float* diag = bkF + (size_t)H * N;          // N floats = 16 KB

    prep<<<dim3(1056), 256, 0, stream>>>(adj, emb, W1, b1, partial, aj, bkF, diag);
    fuse<<<dim3(N / 256, N / 64), 256, 0, stream>>>(W1, aj, bkF, partial, diag,
                                                    W2, b2, out);
}